// Round 5
// baseline (173.565 us; speedup 1.0000x reference)
//
#include <hip/hip_runtime.h>
#include <hip/hip_bf16.h>

// Flash-attention prefill w/ GQA, causal + sliding-window(1024), attention sink.
// B=1, S=2048, Hq=32, Hkv=8, D=128. fp32 in/out; bf16 MFMA compute, fp32 accum.
// R5: 32 q-rows per wave (2-wave blocks, halves LDS read traffic per mfma),
// work-balanced blockIdx->(qb,h) permutation (each CU's 4 blocks sum to exactly
// 102 j-tiles), pre-packed bf16 K/V^T in ws, global_load_lds double-buffer,
// one barrier per iteration, fixed-max softmax.

#define S_LEN 2048
#define DH    128
#define HQ    32
#define HKV   8
#define WIN   1024
#define BR    64
#define BC    32
#define NT    (S_LEN / BC)          // 64 j-tiles
#define FM    16.0f                 // fixed log2-domain softmax max
#define TILE_CH 512                 // 16B chunks per 32x128 bf16 tile

typedef unsigned short u16;
typedef __attribute__((ext_vector_type(8))) short  short8;
typedef __attribute__((ext_vector_type(4))) float  floatx4;
typedef __attribute__((ext_vector_type(4))) unsigned int uintx4;

__device__ __forceinline__ unsigned rne1(float a) {
    unsigned u = __float_as_uint(a);
    return (u + 0x7FFFu + ((u >> 16) & 1u)) >> 16;
}
__device__ __forceinline__ unsigned rne_pk(float a, float b) {
    return rne1(a) | (rne1(b) << 16);
}

// ---------------- pre-pass: pack K/V^T to bf16 in ws ----------------
// Kp[b=hk*64+jt][p]: 16B chunk p holds K[j0+row][hk][cc*8..cc*8+7] bf16 where
//   p = (row<<4) | (cc ^ (row&7)).
// Vtp[b][q]: chunk q holds pairs t=c*4..c*4+3: (V[j0+t][hk][dd], V[j0+t+16][hk][dd])
//   at q = (dd<<2) | (c ^ ((dd>>2)&3)).
__global__ __launch_bounds__(256) void pack_kv(const float* __restrict__ kg,
                                               const float* __restrict__ vg,
                                               u16* __restrict__ kp,
                                               u16* __restrict__ vtp)
{
    __shared__ float Vs[BC][DH + 1];
    const int b   = blockIdx.x;
    const int hk  = b >> 6;
    const int jt  = b & 63;
    const int tid = threadIdx.x;
    const int j0  = jt * BC;

    #pragma unroll
    for (int t = 0; t < 4; t++) {
        int idx = tid + t * 256;        // float4 id 0..1023
        int j   = idx >> 5;
        int dc  = idx & 31;
        floatx4 f = *(const floatx4*)(vg + ((size_t)(j0 + j) * HKV + hk) * DH + dc * 4);
        Vs[j][dc * 4 + 0] = f[0]; Vs[j][dc * 4 + 1] = f[1];
        Vs[j][dc * 4 + 2] = f[2]; Vs[j][dc * 4 + 3] = f[3];
    }

    u16* kpt = kp + (size_t)b * TILE_CH * 8;
    #pragma unroll
    for (int t = 0; t < 2; t++) {
        int c = tid + t * 256;
        int row = c >> 4, cc = c & 15;
        const float* p = kg + ((size_t)(j0 + row) * HKV + hk) * DH + cc * 8;
        floatx4 f0 = *(const floatx4*)p;
        floatx4 f1 = *(const floatx4*)(p + 4);
        int pc = (row << 4) | (cc ^ (row & 7));
        *(uintx4*)(kpt + pc * 8) =
            (uintx4){rne_pk(f0[0], f0[1]), rne_pk(f0[2], f0[3]),
                     rne_pk(f1[0], f1[1]), rne_pk(f1[2], f1[3])};
    }
    __syncthreads();

    u16* vpt = vtp + (size_t)b * TILE_CH * 8;
    #pragma unroll
    for (int t = 0; t < 2; t++) {
        int q  = tid + t * 256;
        int dd = q >> 2, c = q & 3;
        unsigned w0 = rne_pk(Vs[c * 4 + 0][dd], Vs[c * 4 + 16][dd]);
        unsigned w1 = rne_pk(Vs[c * 4 + 1][dd], Vs[c * 4 + 17][dd]);
        unsigned w2 = rne_pk(Vs[c * 4 + 2][dd], Vs[c * 4 + 18][dd]);
        unsigned w3 = rne_pk(Vs[c * 4 + 3][dd], Vs[c * 4 + 19][dd]);
        int qp = (dd << 2) | (c ^ ((dd >> 2) & 3));
        *(uintx4*)(vpt + qp * 8) = (uintx4){w0, w1, w2, w3};
    }
}

// ---------------- main flash kernel: 2 waves x 32 rows ----------------
__launch_bounds__(128, 2)
__global__ void fa_kernel(const float* __restrict__ qg,
                          const u16* __restrict__ kp,
                          const u16* __restrict__ vtp,
                          const float* __restrict__ sg,
                          float* __restrict__ outg)
{
    __shared__ __align__(16) u16 Kt[2][TILE_CH * 8];   // 2 x 8 KB
    __shared__ __align__(16) u16 Vt[2][TILE_CH * 8];   // 2 x 8 KB
    __shared__ __align__(16) u16 Pb[BR * 40];          // 5 KB

    const int tid  = threadIdx.x;
    const int w    = tid >> 6;          // 0..1
    const int lane = tid & 63;
    const int quad = lane >> 4;
    const int l16  = lane & 15;

    // work-balanced (qb,h) mapping: same-CU blocks (bid mod 256) get qb set
    // {u3, 15-u3, 16+u3, 31-u3} -> 102 tiles per CU, flat.
    const int bid = blockIdx.x;
    const int t4  = bid >> 8;
    const int h   = (bid & 255) >> 3;
    const int u3  = bid & 7;
    const int qbt[4] = {u3, 15 - u3, 16 + u3, 31 - u3};
    const int qb  = qbt[t4];

    const int hk = h >> 2;
    const int i0 = qb * BR;
    const int m0 = i0 + w * 32;         // this wave's first q row (32 rows)

    // ---- Q A-fragments: qf[row-half][k] ----
    short8 qf[2][4];
    #pragma unroll
    for (int rh = 0; rh < 2; rh++) {
        const float* qrow = qg + ((size_t)(m0 + rh * 16 + l16) * HQ + h) * DH;
        #pragma unroll
        for (int kk = 0; kk < 4; kk++) {
            const float* p = qrow + kk * 32 + quad * 8;
            floatx4 f0 = *(const floatx4*)p;
            floatx4 f1 = *(const floatx4*)(p + 4);
            uintx4 u = (uintx4){rne_pk(f0[0], f0[1]), rne_pk(f0[2], f0[3]),
                                rne_pk(f1[0], f1[1]), rne_pk(f1[2], f1[3])};
            qf[rh][kk] = *(short8*)&u;
        }
    }

    floatx4 acc[2][8];
    #pragma unroll
    for (int rh = 0; rh < 2; rh++)
        #pragma unroll
        for (int i = 0; i < 8; i++) acc[rh][i] = (floatx4){0.f, 0.f, 0.f, 0.f};
    float l_part[2][4] = {{0.f,0.f,0.f,0.f},{0.f,0.f,0.f,0.f}};

    int jlo = i0 - (WIN - 1); if (jlo < 0) jlo = 0;
    const int jt_lo = jlo >> 5;
    const int jt_hi = (i0 + BR - 1) >> 5;

    const float SC2 = 0.08838834764831845f * 1.4426950408889634f;

    // staging: 128 threads x 4 chunks x 16B per tensor; linear chunk order
    // (wave-uniform base + lane*16) matches global_load_lds lane mapping.
    auto stage = [&](int bb, int jt) {
        const u16* kpt = kp  + ((size_t)(hk * NT + jt)) * TILE_CH * 8;
        const u16* vpt = vtp + ((size_t)(hk * NT + jt)) * TILE_CH * 8;
        #pragma unroll
        for (int it = 0; it < 4; it++) {
            int ch = tid + it * 128;
            __builtin_amdgcn_global_load_lds(
                (const __attribute__((address_space(1))) unsigned*)(kpt + ch * 8),
                (__attribute__((address_space(3))) unsigned*)(&Kt[bb][ch * 8]), 16, 0, 0);
            __builtin_amdgcn_global_load_lds(
                (const __attribute__((address_space(1))) unsigned*)(vpt + ch * 8),
                (__attribute__((address_space(3))) unsigned*)(&Vt[bb][ch * 8]), 16, 0, 0);
        }
    };

    stage(0, jt_lo);
    int bb = 0;

    for (int jt = jt_lo; jt <= jt_hi; jt++) {
        const int j0 = jt << 5;

        __syncthreads();   // drains this wave's global_load_lds (vmcnt(0))

        if (jt < jt_hi) stage(bb ^ 1, jt + 1);   // prefetch next tile

        // ---- QK^T: S[32 rows][32 cols] per wave, 16 mfma, 8 kf reads ----
        floatx4 sc[2][2];
        #pragma unroll
        for (int rh = 0; rh < 2; rh++) {
            sc[rh][0] = (floatx4){0.f, 0.f, 0.f, 0.f};
            sc[rh][1] = (floatx4){0.f, 0.f, 0.f, 0.f};
        }
        #pragma unroll
        for (int kk = 0; kk < 4; kk++) {
            #pragma unroll
            for (int cn = 0; cn < 2; cn++) {
                int row = cn * 16 + l16;
                int cc  = kk * 4 + quad;
                int pc  = (row << 4) | (cc ^ (row & 7));
                short8 kf = *(const short8*)(&Kt[bb][pc * 8]);
                #pragma unroll
                for (int rh = 0; rh < 2; rh++)
                    sc[rh][cn] = __builtin_amdgcn_mfma_f32_16x16x32_bf16(
                        qf[rh][kk], kf, sc[rh][cn], 0, 0, 0);
            }
        }

        // ---- softmax: fixed max, pair-interleaved P (col j | col j+16) ----
        const bool interior = (j0 + (BC - 1) <= i0) && (j0 >= i0 + BR - WIN);
        #pragma unroll
        for (int rh = 0; rh < 2; rh++) {
            const int prow0 = w * 32 + rh * 16 + quad * 4;
            if (interior) {
                #pragma unroll
                for (int r = 0; r < 4; r++) {
                    float p0 = exp2f(fmaf(sc[rh][0][r], SC2, -FM));
                    float p1 = exp2f(fmaf(sc[rh][1][r], SC2, -FM));
                    l_part[rh][r] += p0 + p1;
                    *(unsigned*)(&Pb[(prow0 + r) * 40 + l16 * 2]) = rne_pk(p0, p1);
                }
            } else {
                #pragma unroll
                for (int r = 0; r < 4; r++) {
                    int  i_g = m0 + rh * 16 + quad * 4 + r;
                    bool a0 = (j0 + l16 <= i_g) && (i_g - (j0 + l16) < WIN);
                    bool a1 = (j0 + 16 + l16 <= i_g) && (i_g - (j0 + 16 + l16) < WIN);
                    float p0 = a0 ? exp2f(fmaf(sc[rh][0][r], SC2, -FM)) : 0.f;
                    float p1 = a1 ? exp2f(fmaf(sc[rh][1][r], SC2, -FM)) : 0.f;
                    l_part[rh][r] += p0 + p1;
                    *(unsigned*)(&Pb[(prow0 + r) * 40 + l16 * 2]) = rne_pk(p0, p1);
                }
            }
        }

        // ---- PV: O[32 rows][128 d] per wave, 16 mfma, 8 vf reads ----
        {
            short8 pf[2];
            #pragma unroll
            for (int rh = 0; rh < 2; rh++)
                pf[rh] = *(const short8*)(&Pb[(w * 32 + rh * 16 + l16) * 40 + quad * 8]);
            #pragma unroll
            for (int nf = 0; nf < 8; nf++) {
                int dd = nf * 16 + l16;
                int qp = (dd << 2) | (quad ^ ((dd >> 2) & 3));
                short8 vf = *(const short8*)(&Vt[bb][qp * 8]);
                #pragma unroll
                for (int rh = 0; rh < 2; rh++)
                    acc[rh][nf] = __builtin_amdgcn_mfma_f32_16x16x32_bf16(
                        pf[rh], vf, acc[rh][nf], 0, 0, 0);
            }
        }
        bb ^= 1;
    }

    // ---- epilogue ----
    const float sk2 = exp2f(fmaf(sg[h], 1.4426950408889634f, -FM));
    #pragma unroll
    for (int rh = 0; rh < 2; rh++) {
        float inv[4];
        #pragma unroll
        for (int r = 0; r < 4; r++) {
            float l = l_part[rh][r];
            #pragma unroll
            for (int off = 1; off < 16; off <<= 1)
                l += __shfl_xor(l, off);
            inv[r] = 1.f / (l + sk2);
        }
        #pragma unroll
        for (int nf = 0; nf < 8; nf++) {
            int d = nf * 16 + l16;
            #pragma unroll
            for (int r = 0; r < 4; r++) {
                int ig = m0 + rh * 16 + quad * 4 + r;
                outg[((size_t)ig * HQ + h) * DH + d] = acc[rh][nf][r] * inv[r];
            }
        }
    }
}

// ---------------- fallback (R3-style, used only if ws too small) ----------------
__launch_bounds__(256, 4)
__global__ void fa_fallback(const float* __restrict__ qg,
                            const float* __restrict__ kg,
                            const float* __restrict__ vg,
                            const float* __restrict__ sg,
                            float* __restrict__ outg)
{
    __shared__ __align__(16) u16 Kt[BC * DH];
    __shared__ __align__(16) u16 Vt[DH * BC];
    __shared__ __align__(16) u16 Pb[BR * 40];

    const int tid  = threadIdx.x;
    const int w    = tid >> 6;
    const int lane = tid & 63;
    const int quad = lane >> 4;
    const int l16  = lane & 15;

    const int qb = blockIdx.x / HQ;
    const int h  = blockIdx.x % HQ;
    const int hk = h >> 2;
    const int i0 = qb * BR;
    const int m0 = i0 + w * 16;

    short8 qf[4];
    {
        const float* qrow = qg + ((size_t)(m0 + l16) * HQ + h) * DH;
        #pragma unroll
        for (int kk = 0; kk < 4; kk++) {
            const float* p = qrow + kk * 32 + quad * 8;
            floatx4 f0 = *(const floatx4*)p;
            floatx4 f1 = *(const floatx4*)(p + 4);
            uintx4 u = (uintx4){rne_pk(f0[0], f0[1]), rne_pk(f0[2], f0[3]),
                                rne_pk(f1[0], f1[1]), rne_pk(f1[2], f1[3])};
            qf[kk] = *(short8*)&u;
        }
    }

    floatx4 acc[8];
    #pragma unroll
    for (int i = 0; i < 8; i++) acc[i] = (floatx4){0.f, 0.f, 0.f, 0.f};
    float l_part[4] = {0.f, 0.f, 0.f, 0.f};

    int jlo = i0 - (WIN - 1); if (jlo < 0) jlo = 0;
    const int jt_lo = jlo >> 5;
    const int jt_hi = (i0 + BR - 1) >> 5;
    const float SC2 = 0.08838834764831845f * 1.4426950408889634f;

    for (int jt = jt_lo; jt <= jt_hi; jt++) {
        const int j0 = jt << 5;
        __syncthreads();
        #pragma unroll
        for (int it = 0; it < 2; it++) {
            int g   = tid + 256 * it;
            int row = g >> 4, cc = g & 15;
            int pc  = (row << 4) | (cc ^ (row & 7));
            const float* kpp = kg + ((size_t)(j0 + row) * HKV + hk) * DH + cc * 8;
            floatx4 f0 = *(const floatx4*)kpp;
            floatx4 f1 = *(const floatx4*)(kpp + 4);
            *(uintx4*)(&Kt[pc * 8]) =
                (uintx4){rne_pk(f0[0], f0[1]), rne_pk(f0[2], f0[3]),
                         rne_pk(f1[0], f1[1]), rne_pk(f1[2], f1[3])};
        }
        #pragma unroll
        for (int it = 0; it < 2; it++) {
            int g  = tid + 256 * it;
            int d  = g & 127, jc = g >> 7;
            const float* vp = vg + ((size_t)(j0 + jc * 8) * HKV + hk) * DH + d;
            float e0 = vp[0 * HKV * DH], e1 = vp[1 * HKV * DH];
            float e2 = vp[2 * HKV * DH], e3 = vp[3 * HKV * DH];
            float e4 = vp[4 * HKV * DH], e5 = vp[5 * HKV * DH];
            float e6 = vp[6 * HKV * DH], e7 = vp[7 * HKV * DH];
            int pc = (d << 2) | (jc ^ ((d >> 2) & 3));
            *(uintx4*)(&Vt[pc * 8]) =
                (uintx4){rne_pk(e0, e1), rne_pk(e2, e3), rne_pk(e4, e5), rne_pk(e6, e7)};
        }
        __syncthreads();

        floatx4 sc[2];
        sc[0] = (floatx4){0.f, 0.f, 0.f, 0.f};
        sc[1] = (floatx4){0.f, 0.f, 0.f, 0.f};
        #pragma unroll
        for (int kk = 0; kk < 4; kk++) {
            #pragma unroll
            for (int n = 0; n < 2; n++) {
                int row = n * 16 + l16;
                int cc  = kk * 4 + quad;
                int pc  = (row << 4) | (cc ^ (row & 7));
                short8 kf = *(const short8*)(&Kt[pc * 8]);
                sc[n] = __builtin_amdgcn_mfma_f32_16x16x32_bf16(qf[kk], kf, sc[n], 0, 0, 0);
            }
        }
        #pragma unroll
        for (int r = 0; r < 4; r++) {
            int   i_g = m0 + quad * 4 + r;
            int   jg0 = j0 + l16, jg1 = j0 + 16 + l16;
            bool  a0  = (jg0 <= i_g) && (i_g - jg0 < WIN);
            bool  a1  = (jg1 <= i_g) && (i_g - jg1 < WIN);
            float p0  = a0 ? exp2f(fmaf(sc[0][r], SC2, -FM)) : 0.f;
            float p1  = a1 ? exp2f(fmaf(sc[1][r], SC2, -FM)) : 0.f;
            l_part[r] += p0 + p1;
            int prow = w * 16 + quad * 4 + r;
            *(unsigned*)(&Pb[prow * 40 + 2 * l16]) = rne_pk(p0, p1);
        }
        {
            short8 pf = *(const short8*)(&Pb[(w * 16 + l16) * 40 + quad * 8]);
            #pragma unroll
            for (int nf = 0; nf < 8; nf++) {
                int dd = nf * 16 + l16;
                int qp = (dd << 2) | (quad ^ ((dd >> 2) & 3));
                short8 vf = *(const short8*)(&Vt[qp * 8]);
                acc[nf] = __builtin_amdgcn_mfma_f32_16x16x32_bf16(pf, vf, acc[nf], 0, 0, 0);
            }
        }
    }

    const float sk2 = exp2f(fmaf(sg[h], 1.4426950408889634f, -FM));
    float inv[4];
    #pragma unroll
    for (int r = 0; r < 4; r++) {
        float l = l_part[r];
        #pragma unroll
        for (int off = 1; off < 16; off <<= 1)
            l += __shfl_xor(l, off);
        inv[r] = 1.f / (l + sk2);
    }
    #pragma unroll
    for (int nf = 0; nf < 8; nf++) {
        int d = nf * 16 + l16;
        #pragma unroll
        for (int r = 0; r < 4; r++) {
            int ig = m0 + quad * 4 + r;
            outg[((size_t)ig * HQ + h) * DH + d] = acc[nf][r] * inv[r];
        }
    }
}

extern "C" void kernel_launch(void* const* d_in, const int* in_sizes, int n_in,
                              void* d_out, int out_size, void* d_ws, size_t ws_size,
                              hipStream_t stream) {
    const float* q  = (const float*)d_in[0];
    const float* k  = (const float*)d_in[1];
    const float* v  = (const float*)d_in[2];
    const float* sk = (const float*)d_in[3];
    float* out = (float*)d_out;

    const size_t tile_elems = (size_t)HKV * NT * TILE_CH * 8;   // u16 elems per tensor
    const size_t need = 2 * tile_elems * sizeof(u16);           // 8 MB

    if (ws_size >= need) {
        u16* kp  = (u16*)d_ws;
        u16* vtp = kp + tile_elems;
        pack_kv<<<dim3(HKV * NT), 256, 0, stream>>>(k, v, kp, vtp);
        fa_kernel<<<dim3((S_LEN / BR) * HQ), 128, 0, stream>>>(q, kp, vtp, sk, out);
    } else {
        fa_fallback<<<dim3((S_LEN / BR) * HQ), 256, 0, stream>>>(q, k, v, sk, out);
    }
}

// Round 6
// 163.067 us; speedup vs baseline: 1.0644x; 1.0644x over previous
//
#include <hip/hip_runtime.h>
#include <hip/hip_bf16.h>

// Flash-attention prefill w/ GQA, causal + sliding-window(1024), attention sink.
// B=1, S=2048, Hq=32, Hkv=8, D=128. fp32 in/out; bf16 MFMA compute, fp32 accum.
// R6: R4 compute structure (256 thr, 4 waves x 16 rows, global_load_lds double
// buffer, one barrier/iter, fixed-max softmax) + new dispatch mapping:
//   hk = bid&7  -> XCD-local KV (each XCD's 2MB packed KV fits its 4MB L2)
//   qb set {u5,15-u5,16+u5,31-u5} per CU slot -> exactly 102 j-tiles/CU (flat).

#define S_LEN 2048
#define DH    128
#define HQ    32
#define HKV   8
#define WIN   1024
#define BR    64
#define BC    32
#define NT    (S_LEN / BC)          // 64 j-tiles
#define FM    16.0f                 // fixed log2-domain softmax max
#define TILE_CH 512                 // 16B chunks per 32x128 bf16 tile

typedef unsigned short u16;
typedef __attribute__((ext_vector_type(8))) short  short8;
typedef __attribute__((ext_vector_type(4))) float  floatx4;
typedef __attribute__((ext_vector_type(4))) unsigned int uintx4;

__device__ __forceinline__ unsigned rne1(float a) {
    unsigned u = __float_as_uint(a);
    return (u + 0x7FFFu + ((u >> 16) & 1u)) >> 16;
}
__device__ __forceinline__ unsigned rne_pk(float a, float b) {
    return rne1(a) | (rne1(b) << 16);
}

// ---------------- pre-pass: pack K/V^T to bf16 in ws ----------------
__global__ __launch_bounds__(256) void pack_kv(const float* __restrict__ kg,
                                               const float* __restrict__ vg,
                                               u16* __restrict__ kp,
                                               u16* __restrict__ vtp)
{
    __shared__ float Vs[BC][DH + 1];
    const int b   = blockIdx.x;
    const int hk  = b >> 6;
    const int jt  = b & 63;
    const int tid = threadIdx.x;
    const int j0  = jt * BC;

    #pragma unroll
    for (int t = 0; t < 4; t++) {
        int idx = tid + t * 256;        // float4 id 0..1023
        int j   = idx >> 5;
        int dc  = idx & 31;
        floatx4 f = *(const floatx4*)(vg + ((size_t)(j0 + j) * HKV + hk) * DH + dc * 4);
        Vs[j][dc * 4 + 0] = f[0]; Vs[j][dc * 4 + 1] = f[1];
        Vs[j][dc * 4 + 2] = f[2]; Vs[j][dc * 4 + 3] = f[3];
    }

    u16* kpt = kp + (size_t)b * TILE_CH * 8;
    #pragma unroll
    for (int t = 0; t < 2; t++) {
        int c = tid + t * 256;
        int row = c >> 4, cc = c & 15;
        const float* p = kg + ((size_t)(j0 + row) * HKV + hk) * DH + cc * 8;
        floatx4 f0 = *(const floatx4*)p;
        floatx4 f1 = *(const floatx4*)(p + 4);
        int pc = (row << 4) | (cc ^ (row & 7));
        *(uintx4*)(kpt + pc * 8) =
            (uintx4){rne_pk(f0[0], f0[1]), rne_pk(f0[2], f0[3]),
                     rne_pk(f1[0], f1[1]), rne_pk(f1[2], f1[3])};
    }
    __syncthreads();

    u16* vpt = vtp + (size_t)b * TILE_CH * 8;
    #pragma unroll
    for (int t = 0; t < 2; t++) {
        int q  = tid + t * 256;
        int dd = q >> 2, c = q & 3;
        unsigned w0 = rne_pk(Vs[c * 4 + 0][dd], Vs[c * 4 + 16][dd]);
        unsigned w1 = rne_pk(Vs[c * 4 + 1][dd], Vs[c * 4 + 17][dd]);
        unsigned w2 = rne_pk(Vs[c * 4 + 2][dd], Vs[c * 4 + 18][dd]);
        unsigned w3 = rne_pk(Vs[c * 4 + 3][dd], Vs[c * 4 + 19][dd]);
        int qp = (dd << 2) | (c ^ ((dd >> 2) & 3));
        *(uintx4*)(vpt + qp * 8) = (uintx4){w0, w1, w2, w3};
    }
}

// ---------------- main flash kernel (R4 structure, R6 mapping) ----------------
__launch_bounds__(256, 4)
__global__ void fa_kernel(const float* __restrict__ qg,
                          const u16* __restrict__ kp,
                          const u16* __restrict__ vtp,
                          const float* __restrict__ sg,
                          float* __restrict__ outg)
{
    __shared__ __align__(16) u16 Kt[2][TILE_CH * 8];   // 2 x 8 KB
    __shared__ __align__(16) u16 Vt[2][TILE_CH * 8];   // 2 x 8 KB
    __shared__ __align__(16) u16 Pb[BR * 40];          // 5 KB

    const int tid  = threadIdx.x;
    const int w    = tid >> 6;
    const int lane = tid & 63;
    const int quad = lane >> 4;
    const int l16  = lane & 15;

    // R6 mapping: hk = bid&7 (XCD-local KV); per-CU-slot qb set is balanced.
    const int bid  = blockIdx.x;
    const int hk   = bid & 7;
    const int idx  = bid >> 3;          // 0..127 within this hk
    const int hrem = idx & 3;
    const int u5   = (idx >> 2) & 7;
    const int t4   = idx >> 5;          // 0..3
    const int qbt[4] = {u5, 15 - u5, 16 + u5, 31 - u5};
    const int qb   = qbt[t4];
    const int h    = hk * 4 + hrem;

    const int i0 = qb * BR;
    const int m0 = i0 + w * 16;

    // ---- Q A-fragments (once per block) ----
    short8 qf[4];
    {
        const float* qrow = qg + ((size_t)(m0 + l16) * HQ + h) * DH;
        #pragma unroll
        for (int kk = 0; kk < 4; kk++) {
            const float* p = qrow + kk * 32 + quad * 8;
            floatx4 f0 = *(const floatx4*)p;
            floatx4 f1 = *(const floatx4*)(p + 4);
            uintx4 u = (uintx4){rne_pk(f0[0], f0[1]), rne_pk(f0[2], f0[3]),
                                rne_pk(f1[0], f1[1]), rne_pk(f1[2], f1[3])};
            qf[kk] = *(short8*)&u;
        }
    }

    floatx4 acc[8];
    #pragma unroll
    for (int i = 0; i < 8; i++) acc[i] = (floatx4){0.f, 0.f, 0.f, 0.f};
    float l_part[4] = {0.f, 0.f, 0.f, 0.f};

    int c_r[4];
    #pragma unroll
    for (int r = 0; r < 4; r++) c_r[r] = m0 + quad * 4 + r - l16;  // i_g - l16

    int jlo = i0 - (WIN - 1); if (jlo < 0) jlo = 0;
    const int jt_lo = jlo >> 5;
    const int jt_hi = (i0 + BR - 1) >> 5;

    const float SC2 = 0.08838834764831845f * 1.4426950408889634f;

    const int ch0 = w * 64 + lane;
    auto stage = [&](int bb, int jt) {
        const u16* kpt = kp  + ((size_t)(hk * NT + jt)) * TILE_CH * 8;
        const u16* vpt = vtp + ((size_t)(hk * NT + jt)) * TILE_CH * 8;
        #pragma unroll
        for (int it = 0; it < 2; it++) {
            int ch = ch0 + it * 256;
            __builtin_amdgcn_global_load_lds(
                (const __attribute__((address_space(1))) unsigned*)(kpt + ch * 8),
                (__attribute__((address_space(3))) unsigned*)(&Kt[bb][ch * 8]), 16, 0, 0);
            __builtin_amdgcn_global_load_lds(
                (const __attribute__((address_space(1))) unsigned*)(vpt + ch * 8),
                (__attribute__((address_space(3))) unsigned*)(&Vt[bb][ch * 8]), 16, 0, 0);
        }
    };

    stage(0, jt_lo);
    int bb = 0;

    for (int jt = jt_lo; jt <= jt_hi; jt++) {
        const int j0 = jt << 5;

        __syncthreads();   // drains this wave's global_load_lds (vmcnt(0))

        if (jt < jt_hi) stage(bb ^ 1, jt + 1);   // prefetch next tile

        // ---- QK^T: 8 mfma ----
        floatx4 sc[2];
        sc[0] = (floatx4){0.f, 0.f, 0.f, 0.f};
        sc[1] = (floatx4){0.f, 0.f, 0.f, 0.f};
        #pragma unroll
        for (int kk = 0; kk < 4; kk++) {
            #pragma unroll
            for (int n = 0; n < 2; n++) {
                int row = n * 16 + l16;
                int cc  = kk * 4 + quad;
                int pc  = (row << 4) | (cc ^ (row & 7));
                short8 kf = *(const short8*)(&Kt[bb][pc * 8]);
                sc[n] = __builtin_amdgcn_mfma_f32_16x16x32_bf16(qf[kk], kf, sc[n], 0, 0, 0);
            }
        }

        // ---- softmax: fixed max, pair-interleaved P (col j | col j+16) ----
        const int prow0 = w * 16 + quad * 4;
        const bool interior = (j0 + (BC - 1) <= i0) && (j0 >= i0 + BR - WIN);
        if (interior) {
            #pragma unroll
            for (int r = 0; r < 4; r++) {
                float p0 = exp2f(fmaf(sc[0][r], SC2, -FM));
                float p1 = exp2f(fmaf(sc[1][r], SC2, -FM));
                l_part[r] += p0 + p1;
                *(unsigned*)(&Pb[(prow0 + r) * 40 + l16 * 2]) = rne_pk(p0, p1);
            }
        } else {
            #pragma unroll
            for (int r = 0; r < 4; r++) {
                bool a0 = (j0 <= c_r[r]) && (j0 > c_r[r] - WIN);
                bool a1 = (j0 + 16 <= c_r[r]) && (j0 + 16 > c_r[r] - WIN);
                float p0 = a0 ? exp2f(fmaf(sc[0][r], SC2, -FM)) : 0.f;
                float p1 = a1 ? exp2f(fmaf(sc[1][r], SC2, -FM)) : 0.f;
                l_part[r] += p0 + p1;
                *(unsigned*)(&Pb[(prow0 + r) * 40 + l16 * 2]) = rne_pk(p0, p1);
            }
        }

        // ---- PV: 8 mfma (P via same-wave LDS roundtrip) ----
        {
            short8 pf = *(const short8*)(&Pb[(w * 16 + l16) * 40 + quad * 8]);
            #pragma unroll
            for (int nf = 0; nf < 8; nf++) {
                int dd = nf * 16 + l16;
                int qp = (dd << 2) | (quad ^ ((dd >> 2) & 3));
                short8 vf = *(const short8*)(&Vt[bb][qp * 8]);
                acc[nf] = __builtin_amdgcn_mfma_f32_16x16x32_bf16(pf, vf, acc[nf], 0, 0, 0);
            }
        }
        bb ^= 1;
    }

    // ---- epilogue ----
    const float sk2 = exp2f(fmaf(sg[h], 1.4426950408889634f, -FM));
    float inv[4];
    #pragma unroll
    for (int r = 0; r < 4; r++) {
        float l = l_part[r];
        #pragma unroll
        for (int off = 1; off < 16; off <<= 1)
            l += __shfl_xor(l, off);
        inv[r] = 1.f / (l + sk2);
    }
    #pragma unroll
    for (int nf = 0; nf < 8; nf++) {
        int d = nf * 16 + l16;
        #pragma unroll
        for (int r = 0; r < 4; r++) {
            int ig = m0 + quad * 4 + r;
            outg[((size_t)ig * HQ + h) * DH + d] = acc[nf][r] * inv[r];
        }
    }
}

// ---------------- fallback (used only if ws too small) ----------------
__launch_bounds__(256, 4)
__global__ void fa_fallback(const float* __restrict__ qg,
                            const float* __restrict__ kg,
                            const float* __restrict__ vg,
                            const float* __restrict__ sg,
                            float* __restrict__ outg)
{
    __shared__ __align__(16) u16 Kt[BC * DH];
    __shared__ __align__(16) u16 Vt[DH * BC];
    __shared__ __align__(16) u16 Pb[BR * 40];

    const int tid  = threadIdx.x;
    const int w    = tid >> 6;
    const int lane = tid & 63;
    const int quad = lane >> 4;
    const int l16  = lane & 15;

    const int qb = blockIdx.x / HQ;
    const int h  = blockIdx.x % HQ;
    const int hk = h >> 2;
    const int i0 = qb * BR;
    const int m0 = i0 + w * 16;

    short8 qf[4];
    {
        const float* qrow = qg + ((size_t)(m0 + l16) * HQ + h) * DH;
        #pragma unroll
        for (int kk = 0; kk < 4; kk++) {
            const float* p = qrow + kk * 32 + quad * 8;
            floatx4 f0 = *(const floatx4*)p;
            floatx4 f1 = *(const floatx4*)(p + 4);
            uintx4 u = (uintx4){rne_pk(f0[0], f0[1]), rne_pk(f0[2], f0[3]),
                                rne_pk(f1[0], f1[1]), rne_pk(f1[2], f1[3])};
            qf[kk] = *(short8*)&u;
        }
    }

    floatx4 acc[8];
    #pragma unroll
    for (int i = 0; i < 8; i++) acc[i] = (floatx4){0.f, 0.f, 0.f, 0.f};
    float l_part[4] = {0.f, 0.f, 0.f, 0.f};

    int jlo = i0 - (WIN - 1); if (jlo < 0) jlo = 0;
    const int jt_lo = jlo >> 5;
    const int jt_hi = (i0 + BR - 1) >> 5;
    const float SC2 = 0.08838834764831845f * 1.4426950408889634f;

    for (int jt = jt_lo; jt <= jt_hi; jt++) {
        const int j0 = jt << 5;
        __syncthreads();
        #pragma unroll
        for (int it = 0; it < 2; it++) {
            int g   = tid + 256 * it;
            int row = g >> 4, cc = g & 15;
            int pc  = (row << 4) | (cc ^ (row & 7));
            const float* kpp = kg + ((size_t)(j0 + row) * HKV + hk) * DH + cc * 8;
            floatx4 f0 = *(const floatx4*)kpp;
            floatx4 f1 = *(const floatx4*)(kpp + 4);
            *(uintx4*)(&Kt[pc * 8]) =
                (uintx4){rne_pk(f0[0], f0[1]), rne_pk(f0[2], f0[3]),
                         rne_pk(f1[0], f1[1]), rne_pk(f1[2], f1[3])};
        }
        #pragma unroll
        for (int it = 0; it < 2; it++) {
            int g  = tid + 256 * it;
            int d  = g & 127, jc = g >> 7;
            const float* vp = vg + ((size_t)(j0 + jc * 8) * HKV + hk) * DH + d;
            float e0 = vp[0 * HKV * DH], e1 = vp[1 * HKV * DH];
            float e2 = vp[2 * HKV * DH], e3 = vp[3 * HKV * DH];
            float e4 = vp[4 * HKV * DH], e5 = vp[5 * HKV * DH];
            float e6 = vp[6 * HKV * DH], e7 = vp[7 * HKV * DH];
            int pc = (d << 2) | (jc ^ ((d >> 2) & 3));
            *(uintx4*)(&Vt[pc * 8]) =
                (uintx4){rne_pk(e0, e1), rne_pk(e2, e3), rne_pk(e4, e5), rne_pk(e6, e7)};
        }
        __syncthreads();

        floatx4 sc[2];
        sc[0] = (floatx4){0.f, 0.f, 0.f, 0.f};
        sc[1] = (floatx4){0.f, 0.f, 0.f, 0.f};
        #pragma unroll
        for (int kk = 0; kk < 4; kk++) {
            #pragma unroll
            for (int n = 0; n < 2; n++) {
                int row = n * 16 + l16;
                int cc  = kk * 4 + quad;
                int pc  = (row << 4) | (cc ^ (row & 7));
                short8 kf = *(const short8*)(&Kt[pc * 8]);
                sc[n] = __builtin_amdgcn_mfma_f32_16x16x32_bf16(qf[kk], kf, sc[n], 0, 0, 0);
            }
        }
        #pragma unroll
        for (int r = 0; r < 4; r++) {
            int   i_g = m0 + quad * 4 + r;
            int   jg0 = j0 + l16, jg1 = j0 + 16 + l16;
            bool  a0  = (jg0 <= i_g) && (i_g - jg0 < WIN);
            bool  a1  = (jg1 <= i_g) && (i_g - jg1 < WIN);
            float p0  = a0 ? exp2f(fmaf(sc[0][r], SC2, -FM)) : 0.f;
            float p1  = a1 ? exp2f(fmaf(sc[1][r], SC2, -FM)) : 0.f;
            l_part[r] += p0 + p1;
            int prow = w * 16 + quad * 4 + r;
            *(unsigned*)(&Pb[prow * 40 + 2 * l16]) = rne_pk(p0, p1);
        }
        {
            short8 pf = *(const short8*)(&Pb[(w * 16 + l16) * 40 + quad * 8]);
            #pragma unroll
            for (int nf = 0; nf < 8; nf++) {
                int dd = nf * 16 + l16;
                int qp = (dd << 2) | (quad ^ ((dd >> 2) & 3));
                short8 vf = *(const short8*)(&Vt[qp * 8]);
                acc[nf] = __builtin_amdgcn_mfma_f32_16x16x32_bf16(pf, vf, acc[nf], 0, 0, 0);
            }
        }
    }

    const float sk2 = exp2f(fmaf(sg[h], 1.4426950408889634f, -FM));
    float inv[4];
    #pragma unroll
    for (int r = 0; r < 4; r++) {
        float l = l_part[r];
        #pragma unroll
        for (int off = 1; off < 16; off <<= 1)
            l += __shfl_xor(l, off);
        inv[r] = 1.f / (l + sk2);
    }
    #pragma unroll
    for (int nf = 0; nf < 8; nf++) {
        int d = nf * 16 + l16;
        #pragma unroll
        for (int r = 0; r < 4; r++) {
            int ig = m0 + quad * 4 + r;
            outg[((size_t)ig * HQ + h) * DH + d] = acc[nf][r] * inv[r];
        }
    }
}

extern "C" void kernel_launch(void* const* d_in, const int* in_sizes, int n_in,
                              void* d_out, int out_size, void* d_ws, size_t ws_size,
                              hipStream_t stream) {
    const float* q  = (const float*)d_in[0];
    const float* k  = (const float*)d_in[1];
    const float* v  = (const float*)d_in[2];
    const float* sk = (const float*)d_in[3];
    float* out = (float*)d_out;

    const size_t tile_elems = (size_t)HKV * NT * TILE_CH * 8;   // u16 elems per tensor
    const size_t need = 2 * tile_elems * sizeof(u16);           // 8 MB

    if (ws_size >= need) {
        u16* kp  = (u16*)d_ws;
        u16* vtp = kp + tile_elems;
        pack_kv<<<dim3(HKV * NT), 256, 0, stream>>>(k, v, kp, vtp);
        fa_kernel<<<dim3((S_LEN / BR) * HQ), 256, 0, stream>>>(q, kp, vtp, sk, out);
    } else {
        fa_fallback<<<dim3((S_LEN / BR) * HQ), 256, 0, stream>>>(q, k, v, sk, out);
    }
}